// Round 4
// baseline (246.943 us; speedup 1.0000x reference)
//
#include <hip/hip_runtime.h>

// VQ: z [16384,512] f32, emb [8192,512] f32
// outputs (flat f32): z_q [8388608], loss [1], idx [16384], var [1]

#define BT   16384
#define DIMS 512
#define NE   8192
#define NS   4                       // n-splits
#define BN   256
#define NTPB (NE / NS / BN)          // n-tiles per block = 8
#define NSTEPS 64                    // NTPB * DIMS/64 flat K-steps

// out layout (float elements)
#define LOSS_OFF 8388608
#define IDX_OFF  8388609
#define V_OFF    8404993

// ws layout (bytes)
#define BEST_OFF  0         // u64[16384]
#define ENORM_OFF 131072    // f32[8192]
#define SUMS_OFF  163840    // double[3]
#define CNT_OFF   163864    // unsigned

typedef __attribute__((ext_vector_type(8))) short short8;
typedef __attribute__((ext_vector_type(4))) float floatx4;

#define AS1(p) ((const __attribute__((address_space(1))) void*)(p))
#define AS3(p) ((__attribute__((address_space(3))) void*)(p))

__device__ __forceinline__ unsigned f2bf(float f) {
    unsigned u = __builtin_bit_cast(unsigned, f);
    u += 0x7FFFu + ((u >> 16) & 1u);          // RNE
    return u >> 16;
}

// fused prep: emb->bf16 + ||e||^2 (blocks 0..NE/4), z->bf16 (rest), init best/sums/counter
__global__ __launch_bounds__(256) void prep_kernel(
    const float* __restrict__ z, const float* __restrict__ emb,
    ushort* __restrict__ zh, ushort* __restrict__ ehh,
    float* __restrict__ enorm, unsigned long long* __restrict__ best,
    double* __restrict__ sums, unsigned* __restrict__ counter)
{
    const int lane = threadIdx.x & 63, w = threadIdx.x >> 6;
    const int b = blockIdx.x;
    if (b < NE / 4) {
        const int row = b * 4 + w;
        const float4* p = (const float4*)(emb + (size_t)row * DIMS + lane * 8);
        float4 a = p[0], bb = p[1];
        uint4 h;
        h.x = f2bf(a.x) | (f2bf(a.y) << 16);
        h.y = f2bf(a.z) | (f2bf(a.w) << 16);
        h.z = f2bf(bb.x) | (f2bf(bb.y) << 16);
        h.w = f2bf(bb.z) | (f2bf(bb.w) << 16);
        *(uint4*)(ehh + (size_t)row * DIMS + lane * 8) = h;
        float s = a.x*a.x + a.y*a.y + a.z*a.z + a.w*a.w
                + bb.x*bb.x + bb.y*bb.y + bb.z*bb.z + bb.w*bb.w;
        #pragma unroll
        for (int off = 32; off > 0; off >>= 1) s += __shfl_down(s, off, 64);
        if (lane == 0) enorm[row] = s;
    } else {
        const int row = (b - NE / 4) * 4 + w;
        const float4* p = (const float4*)(z + (size_t)row * DIMS + lane * 8);
        float4 a = p[0], bb = p[1];
        uint4 h;
        h.x = f2bf(a.x) | (f2bf(a.y) << 16);
        h.y = f2bf(a.z) | (f2bf(a.w) << 16);
        h.z = f2bf(bb.x) | (f2bf(bb.y) << 16);
        h.w = f2bf(bb.z) | (f2bf(bb.w) << 16);
        *(uint4*)(zh + (size_t)row * DIMS + lane * 8) = h;
    }
    const int gid = b * 256 + threadIdx.x;
    if (gid < BT) best[gid] = 0xFFFFFFFFFFFFFFFFULL;
    if (gid == 0) { sums[0] = 0.0; sums[1] = 0.0; sums[2] = 0.0; *counter = 0u; }
}

// 256x256-tile 8-wave argmin GEMM — SINGLE barrier per step.
// CHANGE vs prior round: R3 still had two full-block convergences per step
// (mid-step A-restage barrier + boundary barrier), costing ~1900 cy/step of
// serialization over the ~2500 cy pipe floor.  A staging is now 1-ahead
// (A(s+1), opposite-parity buffer) instead of 2-ahead (same-parity), which
// removes the only hazard the mid-step barrier protected.  All stage issues
// (B(s+1) in p0, A(s+1) in p1) happen in the first half of the step, so the
// boundary s_waitcnt vmcnt(0) has >= ~1500 cy of covered latency and the
// step ends with exactly one s_barrier.  Cross-wave safety: each wave
// reaches the barrier only after its own vmcnt(0) (stage writes landed) and
// its p3 LGK(0) (all parity-s reads retired) -> after release, the next
// buffer is fully written and the old buffer is free for restage, for all
// waves.  Frag regs a[4][2]+b[4] = 48 VGPR (same as before).  Per-acc MFMA
// order unchanged (k0 asc, kk0 then kk1) -> bitwise-identical scores,
// tie-break, absmax vs previous rounds.

__device__ __forceinline__ void dsr_fence() {
    asm volatile("s_waitcnt lgkmcnt(0)" ::: "memory");
    __builtin_amdgcn_sched_barrier(0);
}

#define DSR8(dst, IDX) do {                                                    \
    unsigned addr_ = (unsigned)(size_t)AS3(&lds[IDX]);                         \
    asm volatile("ds_read_b128 %0, %1" : "=v"(dst) : "v"(addr_));              \
} while (0)

#define LGK(N_) do {                                                           \
    asm volatile("s_waitcnt lgkmcnt(" #N_ ")" ::: "memory");                   \
    __builtin_amdgcn_sched_barrier(0);                                         \
} while (0)

#define CL4(J_, BIDX_, KK_)                                                    \
    _Pragma("unroll")                                                          \
    for (int mi = 0; mi < 4; mi++)                                             \
        acc[mi][J_] = __builtin_amdgcn_mfma_f32_16x16x32_bf16(                 \
            a[mi][KK_], b[BIDX_], acc[mi][J_], 0, 0, 0);

// staging: dest buffer parity from UNclamped step; source addr clamped
// (tail steps re-load valid data into never-read buffers — branchless)
#define STAGE_A(SA_, H_) do {                                                  \
    const int sa_ = (SA_);                                                     \
    const int sc_ = sa_ & 63;                                                  \
    const unsigned al_ = (unsigned)(sa_ & 1) * 32768u                          \
                       + (unsigned)((((H_) * 128) + w * 8) * 64);              \
    const ushort* g_ = zA + (size_t)((H_) * 128) * DIMS + soff                 \
                     + ((sc_ & 7) * 64);                                       \
    __builtin_amdgcn_global_load_lds(AS1(g_), AS3(&lds[al_]), 16, 0, 0);       \
    __builtin_amdgcn_global_load_lds(AS1(g_ + (size_t)64 * DIMS),              \
                                     AS3(&lds[al_ + 64 * 64]), 16, 0, 0);      \
} while (0)

#define STAGE_B(SB_, H_) do {                                                  \
    const int sb_ = (SB_);                                                     \
    const int sc_ = sb_ & 63;                                                  \
    const unsigned bl_ = 16384u + (unsigned)(sb_ & 1) * 32768u                 \
                       + (unsigned)((((H_) * 128) + w * 8) * 64);              \
    const ushort* g_ = eh + (size_t)(nsN + (sc_ >> 3) * 256 + (H_) * 128) * DIMS \
                     + soff + ((sc_ & 7) * 64);                                \
    __builtin_amdgcn_global_load_lds(AS1(g_), AS3(&lds[bl_]), 16, 0, 0);       \
    __builtin_amdgcn_global_load_lds(AS1(g_ + (size_t)64 * DIMS),              \
                                     AS3(&lds[bl_ + 64 * 64]), 16, 0, 0);      \
} while (0)

// Per-step DS-queue schedule (in-order completion, per wave):
//   p0 issues r1-8  = A kk0 (a[.][0]), B0-3 kk0;  stage B(s+1) h0+h1;
//       clusters J0-3 kk0 wait 3/2/1/0
//   p1 issues r9-16 = B4-7 kk0 (reuse b regs), A kk1 (a[.][1]);
//       stage A(s+1) h0+h1;  clusters J4-7 kk0 wait 7/6/5/4
//   p2 issues r17-20 = B0-3 kk1;  clusters J0-3 kk1 wait 3/2/1/0
//       (LGK(3) also retires r13-16 = A kk1)
//   p3 issues r21-24 = B4-7 kk1;  clusters J4-7 kk1 wait 3/2/1/0
//   vmcnt(0) [loads issued >= half a step earlier]; ONE s_barrier.
// TM_: 0 -> vmcnt(0) boundary wait, 2 -> none (last step; epilogue drains)
#define STEP(S_, AB_, TM_) do {                                                \
    const int s_ = (S_);                                                       \
    short8 a[4][2], b[4];                                                      \
    /* p0 */                                                                   \
    _Pragma("unroll") for (int mi = 0; mi < 4; mi++)                           \
        DSR8(a[mi][0], (AB_) + aro + mi * 1024 + pxo0);                        \
    _Pragma("unroll") for (int j = 0; j < 4; j++)                              \
        DSR8(b[j], 16384u + (AB_) + bro + j * 1024 + pxo0);                    \
    STAGE_B(s_ + 1, 0); STAGE_B(s_ + 1, 1);                                    \
    __builtin_amdgcn_s_setprio(1);                                             \
    LGK(3); CL4(0, 0, 0); LGK(2); CL4(1, 1, 0);                                \
    LGK(1); CL4(2, 2, 0); LGK(0); CL4(3, 3, 0);                                \
    __builtin_amdgcn_s_setprio(0);                                             \
    /* p1 */                                                                   \
    _Pragma("unroll") for (int j = 0; j < 4; j++)                              \
        DSR8(b[j], 16384u + (AB_) + bro + (4 + j) * 1024 + pxo0);              \
    _Pragma("unroll") for (int mi = 0; mi < 4; mi++)                           \
        DSR8(a[mi][1], (AB_) + aro + mi * 1024 + pxo1);                        \
    STAGE_A(s_ + 1, 0); STAGE_A(s_ + 1, 1);                                    \
    __builtin_amdgcn_s_setprio(1);                                             \
    LGK(7); CL4(4, 0, 0); LGK(6); CL4(5, 1, 0);                                \
    LGK(5); CL4(6, 2, 0); LGK(4); CL4(7, 3, 0);                                \
    __builtin_amdgcn_s_setprio(0);                                             \
    /* p2 */                                                                   \
    _Pragma("unroll") for (int j = 0; j < 4; j++)                              \
        DSR8(b[j], 16384u + (AB_) + bro + j * 1024 + pxo1);                    \
    __builtin_amdgcn_s_setprio(1);                                             \
    LGK(3); CL4(0, 0, 1); LGK(2); CL4(1, 1, 1);                                \
    LGK(1); CL4(2, 2, 1); LGK(0); CL4(3, 3, 1);                                \
    __builtin_amdgcn_s_setprio(0);                                             \
    /* p3 */                                                                   \
    _Pragma("unroll") for (int j = 0; j < 4; j++)                              \
        DSR8(b[j], 16384u + (AB_) + bro + (4 + j) * 1024 + pxo1);              \
    __builtin_amdgcn_s_setprio(1);                                             \
    LGK(3); CL4(4, 0, 1); LGK(2); CL4(5, 1, 1);                                \
    LGK(1); CL4(6, 2, 1); LGK(0); CL4(7, 3, 1);                                \
    __builtin_amdgcn_s_setprio(0);                                             \
    __builtin_amdgcn_sched_barrier(0);                                         \
    if ((TM_) == 0) asm volatile("s_waitcnt vmcnt(0)" ::: "memory");           \
    __builtin_amdgcn_s_barrier();                                              \
} while (0)

__global__ __launch_bounds__(512, 2) void argmin_mfma(
    const ushort* __restrict__ zh, const ushort* __restrict__ eh,
    const float* __restrict__ enorm, unsigned long long* __restrict__ best)
{
    // ushort-indexed: A0 [0,16384), B0 [16384,32768), A1 [32768,49152),
    // B1 [49152,65536), enorm f32x2048 [65536,69632). 139264 B total.
    __shared__ __align__(16) ushort lds[69632];
    float* elds = (float*)&lds[65536];

    const int t = threadIdx.x;
    const int w = t >> 6, lane = t & 63;
    const int quad = lane >> 4, l15 = lane & 15;

    // XCD-pairing swizzle (bijective, 256 blocks): each XCD's 32 resident
    // blocks share one 2MB B-panel in its L2.
    const int d = blockIdx.x;
    const int xcd = d & 7, slot = d >> 3;
    const int ns = xcd >> 1;
    const int mt = slot * 2 + (xcd & 1);
    const int m0 = mt * 256;
    const int nsN = ns * (NTPB * BN);         // 2048 * ns

    const int wrow = (w & 3) * 64;            // wave row base in A tile
    const int wcol = (w >> 2) * 128;          // wave col base in B tile

    // enorm -> LDS once (fold must not issue tracked global loads)
    {
        float4 v = *(const float4*)(enorm + nsN + t * 4);
        *(float4*)(elds + t * 4) = v;
    }
    __syncthreads();

    // staging lane geometry (pre-swizzled global source, linear LDS dest)
    const int l8 = lane >> 3, c8 = lane & 7;
    const int chunk = c8 ^ l8;
    const int soff = (w * 8 + l8) * DIMS + chunk * 8;
    const ushort* zA = zh + (size_t)m0 * DIMS;

    // frag-read physical chunk offsets (ushorts): (kk*4+quad)^(l15&7) * 8
    const int pxo0 = (quad ^ (l15 & 7)) * 8;
    const int pxo1 = ((4 + quad) ^ (l15 & 7)) * 8;
    const int aro = (wrow + l15) * 64;
    const int bro = (wcol + l15) * 64;

    floatx4 acc[4][8];
    #pragma unroll
    for (int mi = 0; mi < 4; mi++)
        #pragma unroll
        for (int nj = 0; nj < 8; nj++)
            acc[mi][nj] = (floatx4){0.f, 0.f, 0.f, 0.f};

    float bs[16];
    int   bn_[16];
    #pragma unroll
    for (int k = 0; k < 16; k++) { bs[k] = 3.4e38f; bn_[k] = 0; }

    // prologue: stage step-0 A+B (8 loads), drain, one barrier
    STAGE_A(0, 0); STAGE_A(0, 1);
    STAGE_B(0, 0); STAGE_B(0, 1);
    asm volatile("s_waitcnt vmcnt(0)" ::: "memory");
    __builtin_amdgcn_s_barrier();

    for (int sp = 0; sp < NSTEPS; sp += 2) {
        STEP(sp, 0u, 0);
        STEP(sp + 1, 32768u, (sp == NSTEPS - 2) ? 2 : 0);

        if ((sp & 7) == 6) {
            // n-tile finished: fold scores into running best, reset acc.
            // C/D frag: col = l15 (n), row = quad*4 + r (m).
            const int nt = sp >> 3;
            const int eb = nt * 256 + wcol + l15;
            const int nbase = nsN + eb;
            float en[8];
            #pragma unroll
            for (int nj = 0; nj < 8; nj++) {
                unsigned addr_ = (unsigned)(size_t)AS3(&elds[eb + nj * 16]);
                asm volatile("ds_read_b32 %0, %1" : "=v"(en[nj]) : "v"(addr_));
            }
            dsr_fence();
            #pragma unroll
            for (int nj = 0; nj < 8; nj++) {          // nj asc = n asc
                const int n = nbase + nj * 16;
                #pragma unroll
                for (int mi = 0; mi < 4; mi++) {
                    #pragma unroll
                    for (int r = 0; r < 4; r++) {
                        const int k = mi * 4 + r;
                        const float sc = fmaf(-2.0f, acc[mi][nj][r], en[nj]);
                        if (sc < bs[k]) { bs[k] = sc; bn_[k] = n; }
                    }
                    acc[mi][nj] = (floatx4){0.f, 0.f, 0.f, 0.f};
                }
            }
        }
    }

    // drain tail staging gloads before epilogue/endpgm (once, cheap)
    asm volatile("s_waitcnt vmcnt(0)" ::: "memory");

    // once per block: pack, shfl-min over l15 group, atomicMin across splits
    #pragma unroll
    for (int mi = 0; mi < 4; mi++)
        #pragma unroll
        for (int r = 0; r < 4; r++) {
            const int k = mi * 4 + r;
            unsigned su = __builtin_bit_cast(unsigned, bs[k]);
            su = (su & 0x80000000u) ? ~su : (su | 0x80000000u);  // order-preserving
            unsigned long long key = ((unsigned long long)su << 32) | (unsigned)bn_[k];
            #pragma unroll
            for (int off = 1; off < 16; off <<= 1) {
                unsigned long long o = __shfl_xor(key, off, 64);
                key = (o < key) ? o : key;
            }
            if (l15 == 0) atomicMin(&best[m0 + wrow + mi * 16 + quad * 4 + r], key);
        }
}

// one block per 32 rows: idx from packed keys, gather z_q, loss + idx stats;
// last block to finish runs the finalize.
__global__ __launch_bounds__(256) void gather_loss_kernel(
    const float* __restrict__ z, const float* __restrict__ emb,
    const unsigned long long* __restrict__ best,
    float* __restrict__ out, double* __restrict__ sums, unsigned* __restrict__ counter)
{
    __shared__ int sIdx[32];
    __shared__ double red[4];
    const int t = threadIdx.x;
    const int row0 = blockIdx.x * 32;
    double myIdxSum = 0.0, myIdxSq = 0.0;
    if (t < 32) {
        int row = row0 + t;
        int idx = (int)(unsigned)(best[row] & 0xFFFFFFFFULL);
        sIdx[t] = idx;
        out[IDX_OFF + row] = (float)idx;
        myIdxSum = (double)idx;
        myIdxSq = (double)idx * (double)idx;
    }
    __syncthreads();
    double acc = 0.0;
    #pragma unroll 4
    for (int i = 0; i < 16; i++) {
        int e = i * 1024 + t * 4;        // 32 rows x 512 = 16384 elems per block
        int rl = e >> 9;
        int c = e & 511;
        int idx = sIdx[rl];
        float4 zv = *(const float4*)(z + (size_t)(row0 + rl) * DIMS + c);
        float4 ev = *(const float4*)(emb + (size_t)idx * DIMS + c);
        *(float4*)(out + (size_t)(row0 + rl) * DIMS + c) = ev;  // z_q_st value == z_q
        float dx = zv.x - ev.x, dy = zv.y - ev.y;
        float dz = zv.z - ev.z, dw = zv.w - ev.w;
        acc += (double)(dx * dx + dy * dy) + (double)(dz * dz + dw * dw);
    }
    const int lane = t & 63, wv = t >> 6;
    #pragma unroll
    for (int off = 32; off > 0; off >>= 1) {
        acc      += __shfl_down(acc, off, 64);
        myIdxSum += __shfl_down(myIdxSum, off, 64);
        myIdxSq  += __shfl_down(myIdxSq, off, 64);
    }
    if (lane == 0) red[wv] = acc;
    __syncthreads();
    if (t == 0) {
        double tot = red[0] + red[1] + red[2] + red[3];
        atomicAdd(&sums[0], tot);
        atomicAdd(&sums[1], myIdxSum);   // wave 0 held all idx stats
        atomicAdd(&sums[2], myIdxSq);
        __threadfence();
        unsigned old = atomicAdd(counter, 1u);
        if (old == gridDim.x - 1) {
            __threadfence();
            double s0 = atomicAdd(&sums[0], 0.0);
            double s1 = atomicAdd(&sums[1], 0.0);
            double s2 = atomicAdd(&sums[2], 0.0);
            out[LOSS_OFF] = (float)(1.25 * s0 / (double)((size_t)BT * DIMS));
            double m = s1 / (double)BT;
            out[V_OFF] = (float)(s2 / (double)BT - m * m);
        }
    }
}

extern "C" void kernel_launch(void* const* d_in, const int* in_sizes, int n_in,
                              void* d_out, int out_size, void* d_ws, size_t ws_size,
                              hipStream_t stream) {
    const float* z = (const float*)d_in[0];
    const float* emb = (const float*)d_in[1];
    float* out = (float*)d_out;
    char* ws = (char*)d_ws;
    unsigned long long* best = (unsigned long long*)(ws + BEST_OFF);
    float* enorm  = (float*)(ws + ENORM_OFF);
    double* sums  = (double*)(ws + SUMS_OFF);
    unsigned* counter = (unsigned*)(ws + CNT_OFF);

    // bf16 scratch in the z_q region of out (fully overwritten by gather at the end)
    ushort* zh = (ushort*)out;
    ushort* ehh = zh + (size_t)BT * DIMS;

    hipLaunchKernelGGL(prep_kernel, dim3(NE / 4 + BT / 4), dim3(256), 0, stream,
                       z, emb, zh, ehh, enorm, best, sums, counter);
    hipLaunchKernelGGL(argmin_mfma, dim3(256), dim3(512), 0, stream,
                       zh, ehh, enorm, best);
    hipLaunchKernelGGL(gather_loss_kernel, dim3(BT / 32), dim3(256), 0, stream,
                       z, emb, best, out, sums, counter);
}